// Round 13
// baseline (245.822 us; speedup 1.0000x reference)
//
#include <hip/hip_runtime.h>
#include <hip/hip_bf16.h>

// LocalAttention (T5-style blocked local attention).
// T=4096, B=4, C=1024, H=16, D=64, L=128, NB=32, window = 3 blocks = 384 keys.
//
// Round 12: XCD-chunked block swizzle for both GEMMs. r11 PMC: gemm<3> at
// MfmaUtil 40% with ~768MB of L2-fill streaming from L3 under default
// round-robin block->XCD placement. Remap L -> (L&7)*chunk + L>>3 (bijective)
// with y-fastest decode: ~12 consecutive co-XCD blocks share one A-tile in
// L2, and the v^T path's B panel == the q/k path's A tile (same xb rows).
// attn (r10 LDS-staged, softmax-lite) and conv_xw unchanged.

#define T_LEN 4096
#define BATCH 4
#define CDIM 1024
#define NHEAD 16
#define HDIM 64
#define BLK 128
#define NBLK 32
#define LOG2E 1.4426950408889634f

typedef __attribute__((ext_vector_type(8))) short bf16x8;
typedef __attribute__((ext_vector_type(4))) float f32x4;

__device__ __forceinline__ unsigned short f2b(float f) {
    __hip_bfloat16 h = __float2bfloat16(f);
    return *reinterpret_cast<unsigned short*>(&h);
}
__device__ __forceinline__ float exp2_fast(float x) {
    float r;
    asm("v_exp_f32 %0, %1" : "=v"(r) : "v"(x));
    return r;
}
__device__ __forceinline__ void gl_lds16(const void* g, void* l) {
    __builtin_amdgcn_global_load_lds(
        (const __attribute__((address_space(1))) unsigned int*)g,
        (__attribute__((address_space(3))) unsigned int*)l, 16, 0, 0);
}

// ---- merged conversion kernel ----
// bid < 8192 : conv_x  — hidden (T,B,C) fp32 -> xb bf16 [m=b*T+t][k=c]
// bid >= 8192: conv_w  — W fp32 [k][n] -> wt bf16 [n][k], Wq scaled 0.125*log2e
__global__ __launch_bounds__(256) void conv_xw(
    const float* __restrict__ hidden,
    const float* __restrict__ W0, const float* __restrict__ W1,
    const float* __restrict__ W2, const float* __restrict__ W3,
    unsigned short* __restrict__ xb, unsigned short* __restrict__ wt)
{
    __shared__ float tile[32][33];
    const int bid = blockIdx.x;
    if (bid < 8192) {
        int chunk = bid * 256 + threadIdx.x;
        int c8 = chunk & 127;
        int rem = chunk >> 7;                          // = t*4 + b
        int b = rem & 3;
        int t = rem >> 2;
        const float* src = hidden + ((size_t)rem << 10) + c8 * 8;
        float4 v0 = *(const float4*)src;
        float4 v1 = *(const float4*)(src + 4);
        bf16x8 o;
        o[0] = (short)f2b(v0.x); o[1] = (short)f2b(v0.y);
        o[2] = (short)f2b(v0.z); o[3] = (short)f2b(v0.w);
        o[4] = (short)f2b(v1.x); o[5] = (short)f2b(v1.y);
        o[6] = (short)f2b(v1.z); o[7] = (short)f2b(v1.w);
        *(bf16x8*)&xb[((size_t)(b * T_LEN + t) << 10) + c8 * 8] = o;
    } else {
        const int id = bid - 8192;                     // 0..4095
        const int z = id >> 10;
        const int rem = id & 1023;
        const int k0 = (rem & 31) * 32;
        const int n0 = (rem >> 5) * 32;
        const float* W = (z == 0) ? W0 : (z == 1) ? W1 : (z == 2) ? W2 : W3;
        const float scale = (z == 0) ? 0.125f * LOG2E : 1.0f;
        unsigned short* hi = wt + (size_t)z * (CDIM * CDIM);
        const int r = threadIdx.x >> 5;   // 0..7
        const int c = threadIdx.x & 31;
#pragma unroll
        for (int i = 0; i < 4; ++i)
            tile[r + i * 8][c] = W[(size_t)(k0 + r + i * 8) * CDIM + n0 + c] * scale;
        __syncthreads();
#pragma unroll
        for (int i = 0; i < 4; ++i) {
            int nn = r + i * 8;
            hi[(size_t)(n0 + nn) * CDIM + k0 + c] = f2b(tile[c][nn]);
        }
    }
}

// ================= 8-phase 256x256 GEMM (bf16 MFMA) =================
// MODE 1: out_proj. A = ao [16384][1024], B = WoT, fp32 transposed out.
// MODE 3: fused qkv. y<8: A = xb, B = wt (WqT|WkT), scatter bf16 to qb/kb.
//         y>=8: A = wt+2M (WvT), B = xb (operand-swapped), writes vT[b][h][d][t].

#define STAGE(pb, tau, half, isB) do {                                         \
    const unsigned short* _gb = (isB) ? Bg : Ag;                               \
    const int _bo = (pb) * 32768 + (isB) * 16384 + (half) * 8192;              \
    gl_lds16(_gb + (size_t)((half) * 128 + sr) * 1024 + (tau) * 64,            \
             (short*)lds + _bo + ldsW);                                        \
    gl_lds16(_gb + (size_t)((half) * 128 + 64 + sr) * 1024 + (tau) * 64,       \
             (short*)lds + _bo + 4096 + ldsW);                                 \
} while (0)

#define LDB(p) do {                                                            \
    _Pragma("unroll") for (int nr = 0; nr < 4; ++nr) {                         \
        int _row = wc * 64 + nr * 16 + li;                                     \
        _Pragma("unroll") for (int ks = 0; ks < 2; ++ks)                       \
            bkf[nr][ks] = *(const bf16x8*)(ldsc + (p) * 65536 + 32768 +        \
                ((_row * 128 + ks * 64 + g * 16) ^ swz));                      \
    } } while (0)

#define LDA(p, q) do {                                                         \
    _Pragma("unroll") for (int dm = 0; dm < 2; ++dm) {                         \
        int _row = wr * 128 + ((q) * 2 + dm) * 16 + li;                        \
        _Pragma("unroll") for (int ks = 0; ks < 2; ++ks)                       \
            af[dm][ks] = *(const bf16x8*)(ldsc + (p) * 65536 +                 \
                ((_row * 128 + ks * 64 + g * 16) ^ swz));                      \
    } } while (0)

#define MM(q) do {                                                             \
    _Pragma("unroll") for (int dm = 0; dm < 2; ++dm)                           \
    _Pragma("unroll") for (int nr = 0; nr < 4; ++nr) {                         \
        acc[(q)*2+dm][nr] = __builtin_amdgcn_mfma_f32_16x16x32_bf16(           \
            af[dm][0], bkf[nr][0], acc[(q)*2+dm][nr], 0, 0, 0);                \
        acc[(q)*2+dm][nr] = __builtin_amdgcn_mfma_f32_16x16x32_bf16(           \
            af[dm][1], bkf[nr][1], acc[(q)*2+dm][nr], 0, 0, 0);                \
    } } while (0)

#define MID() do {                                                             \
    __builtin_amdgcn_s_barrier();                                              \
    asm volatile("s_waitcnt lgkmcnt(0)" ::: "memory");                         \
    __builtin_amdgcn_sched_barrier(0);                                         \
    __builtin_amdgcn_s_setprio(1);                                             \
} while (0)

#define TAIL() do {                                                            \
    __builtin_amdgcn_s_setprio(0);                                             \
    __builtin_amdgcn_sched_barrier(0);                                         \
    __builtin_amdgcn_s_barrier();                                              \
} while (0)

template<int MODE>
__global__ __launch_bounds__(512, 1) void gemm_8ph(
    const unsigned short* __restrict__ Am,
    const unsigned short* __restrict__ Bm,
    unsigned short* __restrict__ qb, unsigned short* __restrict__ kb,
    unsigned short* __restrict__ vT, float* __restrict__ fout)
{
    __shared__ short lds[65536];   // 128 KB: [buf:2][A 256x64 | B 256x64]

    const int tid = threadIdx.x;
    const int w = tid >> 6, lane = tid & 63;
    const int g = lane >> 4, li = lane & 15;
    const int wr = w >> 2, wc = w & 3;           // 2 x 4 wave grid

    // XCD-chunked swizzle: hardware linear id L -> work id, y-fastest within
    // each XCD chunk so consecutive co-XCD blocks share the A-tile in L2
    // (and the v-path's B panel == the q/k path's A tile: same xb rows).
    const int L = blockIdx.y * gridDim.x + blockIdx.x;
    bool isV = false;
    int m0, n0;
    const unsigned short *Abase, *Bbase;
    if (MODE == 3) {
        const int wrk = (L & 7) * 96 + (L >> 3);   // 768 blocks, bijective
        const int x = wrk / 12, y = wrk % 12;
        isV = (y >= 8);
        if (isV) {
            Abase = Bm + 2 * (size_t)(CDIM * CDIM);   // WvT
            Bbase = Am;                               // xb
            m0 = (y - 8) * 256;                       // over M=1024
            n0 = x * 256;                             // over N=16384
        } else {
            Abase = Am;                               // xb
            Bbase = Bm;                               // WqT|WkT
            m0 = x * 256;
            n0 = y * 256;                             // over N=2048
        }
    } else {
        const int wrk = (L & 7) * 32 + (L >> 3);   // 256 blocks, bijective
        const int x = wrk >> 2, y = wrk & 3;
        Abase = Am; Bbase = Bm;
        m0 = x * 256;
        n0 = y * 256;
    }

    const int sr = tid >> 3;                       // 0..63
    const int cbs = ((tid & 7) * 16) ^ ((sr & 7) << 4);
    const int ldsW = w * 512;                      // shorts (wave-uniform)
    const unsigned short* Ag = Abase + (size_t)m0 * 1024 + (cbs >> 1);
    const unsigned short* Bg = Bbase + (size_t)n0 * 1024 + (cbs >> 1);

    const char* ldsc = (const char*)lds;
    const int swz = (li & 7) << 4;

    f32x4 acc[8][4];
#pragma unroll
    for (int a = 0; a < 8; ++a)
#pragma unroll
        for (int b = 0; b < 4; ++b) acc[a][b] = (f32x4){0.f, 0.f, 0.f, 0.f};

    bf16x8 bkf[4][2];
    bf16x8 af[2][2];

    // prologue: tile0 fully + B halves of tile1; drain tile0 (4 loads left)
    STAGE(0, 0, 0, 0); STAGE(0, 0, 1, 0);
    STAGE(0, 0, 0, 1); STAGE(0, 0, 1, 1);
    STAGE(1, 1, 0, 1); STAGE(1, 1, 1, 1);
    asm volatile("s_waitcnt vmcnt(4)" ::: "memory");
    __builtin_amdgcn_s_barrier();

#pragma unroll 1
    for (int i = 0; i < 8; ++i) {
        const int o = 2 * i + 1, e2 = 2 * i + 2, o2 = 2 * i + 3;
        const bool pf = (i < 7);
        // ---- even tile (buf0) ----
        LDB(0); LDA(0, 0); STAGE(1, o, 0, 0); MID(); MM(0); TAIL();
        LDA(0, 1); STAGE(1, o, 1, 0); MID(); MM(1); TAIL();
        LDA(0, 2); if (pf) STAGE(0, e2, 0, 1); MID(); MM(2); TAIL();
        LDA(0, 3); if (pf) STAGE(0, e2, 1, 1); MID(); MM(3);
        __builtin_amdgcn_s_setprio(0);
        __builtin_amdgcn_sched_barrier(0);
        if (pf) asm volatile("s_waitcnt vmcnt(4)" ::: "memory");
        else    asm volatile("s_waitcnt vmcnt(0)" ::: "memory");
        __builtin_amdgcn_s_barrier();
        // ---- odd tile (buf1) ----
        LDB(1); LDA(1, 0); if (pf) STAGE(0, e2, 0, 0); MID(); MM(0); TAIL();
        LDA(1, 1); if (pf) STAGE(0, e2, 1, 0); MID(); MM(1); TAIL();
        LDA(1, 2); if (pf) STAGE(1, o2, 0, 1); MID(); MM(2); TAIL();
        LDA(1, 3); if (pf) STAGE(1, o2, 1, 1); MID(); MM(3);
        __builtin_amdgcn_s_setprio(0);
        __builtin_amdgcn_sched_barrier(0);
        if (pf) asm volatile("s_waitcnt vmcnt(4)" ::: "memory");
        else    asm volatile("s_waitcnt vmcnt(0)" ::: "memory");
        __builtin_amdgcn_s_barrier();
    }

    if (MODE == 3 && !isV) {
        const int nA = n0 + wc * 64;
        const int hh = (nA & 1023) >> 6;
        unsigned short* ob = ((nA >> 10) == 0) ? qb : kb;
#pragma unroll
        for (int mr = 0; mr < 8; ++mr)
#pragma unroll
            for (int reg = 0; reg < 4; ++reg) {
                int m = m0 + wr * 128 + mr * 16 + g * 4 + reg;
                size_t ro = ((size_t)((m >> 12) * NHEAD + hh) * T_LEN + (m & 4095)) * HDIM;
#pragma unroll
                for (int nr = 0; nr < 4; ++nr)
                    ob[ro + nr * 16 + li] = f2b(acc[mr][nr][reg]);
            }
    } else if (MODE == 3) {
        // v^T: m = Wv-row = h*64+d; n = xb-row = b*4096+t
#pragma unroll
        for (int mr = 0; mr < 8; ++mr)
#pragma unroll
            for (int reg = 0; reg < 4; ++reg) {
                int m = m0 + wr * 128 + mr * 16 + g * 4 + reg;
#pragma unroll
                for (int nr = 0; nr < 4; ++nr) {
                    int nn = n0 + wc * 64 + nr * 16 + li;
                    vT[((size_t)((nn >> 12) * 1024 + m) << 12) + (nn & 4095)] =
                        f2b(acc[mr][nr][reg]);
                }
            }
    } else {
#pragma unroll
        for (int mr = 0; mr < 8; ++mr)
#pragma unroll
            for (int reg = 0; reg < 4; ++reg) {
                int m = m0 + wr * 128 + mr * 16 + g * 4 + reg;
                float* orow = fout + ((size_t)(m & 4095) * BATCH + (m >> 12)) * CDIM
                              + n0 + wc * 64;
#pragma unroll
                for (int nr = 0; nr < 4; ++nr)
                    orow[nr * 16 + li] = acc[mr][nr][reg];
            }
    }
}

// ---------------- relative position bucket (== reference fp32 log formula) ----
__device__ __forceinline__ int rel_bucket(int rel) {
    int rb = (rel > 0) ? 16 : 0;
    int rp = abs(rel);
    int bu;
    if (rp < 8) bu = rp;
    else if (rp < 12) bu = 8;
    else if (rp < 16) bu = 9;
    else if (rp < 23) bu = 10;
    else if (rp < 32) bu = 11;
    else if (rp < 46) bu = 12;
    else if (rp < 64) bu = 13;
    else if (rp < 91) bu = 14;
    else bu = 15;
    return rb + bu;
}

// ---------------- MFMA attention: LDS-staged K/V, double-buffered ----------------
// grid 2048 (XCD-swizzled), 256 threads = 4 waves; wave w owns q-rows
// [32w,32w+32). K tile [64key][64d], V tile [64d][64t] staged via gl_lds with
// the gemm swizzle; stage(kt+1) issued at iter start, drained by the
// end-of-iter __syncthreads(). Softmax-lite (exp2 domain, deferred l-reduce).
#define PL_STR 72

__global__ __launch_bounds__(256) void attn_mfma(
    const unsigned short* __restrict__ qb, const unsigned short* __restrict__ kb,
    const unsigned short* __restrict__ vT, const float* __restrict__ table,
    unsigned short* __restrict__ ao)
{
    // bijective XCD swizzle: consecutive logical blocks (same b,h panel)
    // land on the same XCD (2048 % 8 == 0)
    const int bid = blockIdx.x;
    const int lb = (bid & 7) * 256 + (bid >> 3);
    const int n = lb & 31;
    const int h = (lb >> 5) & 15;
    const int b = lb >> 9;
    const int tid = threadIdx.x;
    const int w = tid >> 6;
    const int lane = tid & 63;
    const int g = lane >> 4;
    const int li = lane & 15;

    __shared__ short kvS[2][2][4096];   // [buf][K|V][64x64], 32 KB
    __shared__ short Pl[4][32 * PL_STR];
    __shared__ float ldsb[512];

    for (int i = tid; i < 512; i += 256)
        ldsb[i] = table[rel_bucket(i - 255) * NHEAD + h] * LOG2E;

    const unsigned short* qBase =
        qb + (((size_t)b * NHEAD + h) * T_LEN + (size_t)n * BLK) * HDIM;
    const unsigned short* kBase = kb + ((size_t)b * NHEAD + h) * T_LEN * HDIM;
    const unsigned short* vTBase = vT + ((size_t)b * NHEAD + h) * (size_t)HDIM * T_LEN;

    // staging geometry: row = u*32 + w*8 + (lane>>3)
    const int srow = lane >> 3;                               // 0..7
    const int scol = (((lane & 7) * 16) ^ (srow << 4)) >> 1;  // swizzled, shorts
    const int swz = (li & 7) << 4;                            // read-side XOR

#define STAGEKV(pb, tk0) do {                                                  \
    _Pragma("unroll") for (int u = 0; u < 2; ++u) {                            \
        int _r = u * 32 + w * 8 + srow;                                        \
        gl_lds16(kBase + (size_t)((tk0) + _r) * HDIM + scol,                   \
                 &kvS[pb][0][u * 2048 + w * 512]);                             \
        gl_lds16(vTBase + (size_t)_r * T_LEN + (tk0) + scol,                   \
                 &kvS[pb][1][u * 2048 + w * 512]);                             \
    } } while (0)

    bf16x8 aq[2][2];
#pragma unroll
    for (int mi = 0; mi < 2; ++mi)
#pragma unroll
        for (int ks = 0; ks < 2; ++ks)
            aq[mi][ks] = *(const bf16x8*)(qBase +
                (size_t)(w * 32 + mi * 16 + li) * HDIM + ks * 32 + g * 8);

    f32x4 oacc[2][4];
    float lp[2][4];
#pragma unroll
    for (int mi = 0; mi < 2; ++mi)
#pragma unroll
        for (int r4 = 0; r4 < 4; ++r4) {
            oacc[mi][r4] = (f32x4){0.f, 0.f, 0.f, 0.f};
            lp[mi][r4] = 0.f;
        }

    const int tkbase = (n - 1) * BLK;
    if (tkbase >= 0) STAGEKV(0, tkbase);
    __syncthreads();   // tile0 staged (also covers ldsb)

#pragma unroll
    for (int kt = 0; kt < 6; ++kt) {
        const int tk0 = tkbase + kt * 64;
        const bool inb = (tk0 >= 0) && (tk0 < T_LEN);   // block-uniform
        const int cur = kt & 1;

        // issue next tile's stage (drains into end-of-iter barrier)
        if (kt < 5) {
            const int tkn = tk0 + 64;
            if (tkn >= 0 && tkn < T_LEN) STAGEKV(cur ^ 1, tkn);
        }

        const char* kbufC = (const char*)kvS[cur][0];
        const char* vbufC = (const char*)kvS[cur][1];

        // ---- S = Q K^T (log2 domain; swizzled ds_read frags) ----
        f32x4 sacc[2][4];
#pragma unroll
        for (int mi = 0; mi < 2; ++mi)
#pragma unroll
            for (int ni = 0; ni < 4; ++ni)
                sacc[mi][ni] = (f32x4){0.f, 0.f, 0.f, 0.f};
        if (inb) {
            __builtin_amdgcn_s_setprio(1);
#pragma unroll
            for (int ks = 0; ks < 2; ++ks) {
                bf16x8 bk[4];
#pragma unroll
                for (int ni = 0; ni < 4; ++ni)
                    bk[ni] = *(const bf16x8*)(kbufC +
                        ((ni * 16 + li) * 128 + ((ks * 64 + g * 16) ^ swz)));
#pragma unroll
                for (int mi = 0; mi < 2; ++mi)
#pragma unroll
                    for (int ni = 0; ni < 4; ++ni)
                        sacc[mi][ni] = __builtin_amdgcn_mfma_f32_16x16x32_bf16(
                            aq[mi][ks], bk[ni], sacc[mi][ni], 0, 0, 0);
            }
            __builtin_amdgcn_s_setprio(0);
        }

        // ---- p = exp2(s + bias'); per-lane l; store P bf16 ----
#pragma unroll
        for (int mi = 0; mi < 2; ++mi) {
            const int rq = w * 32 + mi * 16 + g * 4;
#pragma unroll
            for (int reg = 0; reg < 4; ++reg) {
                const int r = rq + reg;
                const float* lbp = ldsb + (kt * 64 + li - r + 127);
                float p0 = exp2_fast(sacc[mi][0][reg] + lbp[0]);
                float p1 = exp2_fast(sacc[mi][1][reg] + lbp[16]);
                float p2 = exp2_fast(sacc[mi][2][reg] + lbp[32]);
                float p3 = exp2_fast(sacc[mi][3][reg] + lbp[48]);
                lp[mi][reg] += (p0 + p1) + (p2 + p3);
                short* pr = &Pl[w][(mi * 16 + g * 4 + reg) * PL_STR + li];
                pr[0]  = (short)f2b(p0);
                pr[16] = (short)f2b(p1);
                pr[32] = (short)f2b(p2);
                pr[48] = (short)f2b(p3);
            }
        }

        // ---- O += P V (V frags from LDS; skip OOB tiles: V == 0) ----
        if (inb) {
            __builtin_amdgcn_s_setprio(1);
#pragma unroll
            for (int ks = 0; ks < 2; ++ks) {
                bf16x8 ap[2], bv[4];
#pragma unroll
                for (int mi = 0; mi < 2; ++mi)
                    ap[mi] = *(bf16x8*)&Pl[w][(mi * 16 + li) * PL_STR + ks * 32 + g * 8];
#pragma unroll
                for (int dn = 0; dn < 4; ++dn)
                    bv[dn] = *(const bf16x8*)(vbufC +
                        ((dn * 16 + li) * 128 + ((ks * 64 + g * 16) ^ swz)));
#pragma unroll
                for (int mi = 0; mi < 2; ++mi)
#pragma unroll
                    for (int dn = 0; dn < 4; ++dn)
                        oacc[mi][dn] = __builtin_amdgcn_mfma_f32_16x16x32_bf16(
                            ap[mi], bv[dn], oacc[mi][dn], 0, 0, 0);
            }
            __builtin_amdgcn_s_setprio(0);
        }

        __syncthreads();   // next-tile stage drained; buf[cur] free for reuse
    }

    // ---- one deferred l-reduce + normalize + write out ----
#pragma unroll
    for (int mi = 0; mi < 2; ++mi) {
#pragma unroll
        for (int reg = 0; reg < 4; ++reg) {
            float l = lp[mi][reg];
            l += __shfl_xor(l, 1);
            l += __shfl_xor(l, 2);
            l += __shfl_xor(l, 4);
            l += __shfl_xor(l, 8);
            float inv = 1.f / l;
            int t = n * BLK + w * 32 + mi * 16 + g * 4 + reg;
            unsigned short* orow = ao + ((size_t)b * T_LEN + t) * CDIM + h * HDIM;
#pragma unroll
            for (int dn = 0; dn < 4; ++dn)
                orow[dn * 16 + li] = f2b(oacc[mi][dn][reg] * inv);
        }
    }
#undef STAGEKV
}

extern "C" void kernel_launch(void* const* d_in, const int* in_sizes, int n_in,
                              void* d_out, int out_size, void* d_ws, size_t ws_size,
                              hipStream_t stream) {
    const float* hidden = (const float*)d_in[0];
    const float* Wq = (const float*)d_in[1];
    const float* Wk = (const float*)d_in[2];
    const float* Wv = (const float*)d_in[3];
    const float* Wo = (const float*)d_in[4];
    const float* table = (const float*)d_in[5];
    float* out = (float*)d_out;

    const size_t qkvElems = (size_t)BATCH * NHEAD * T_LEN * HDIM;   // 16.78M
    const size_t wElems = (size_t)CDIM * CDIM;                      // 1.05M
    const size_t needed = (4 * qkvElems + 4 * wElems) * 2;          // ~136 MiB
    if (ws_size < needed) return;

    unsigned short* qb = (unsigned short*)d_ws;
    unsigned short* kb = qb + qkvElems;
    unsigned short* vT = kb + qkvElems;     // [b][h][d][t]
    unsigned short* xb = vT + qkvElems;     // reused as ao after proj
    unsigned short* wt = xb + qkvElems;     // [WqT|WkT|WvT|WoT], each [1024][1024]

    conv_xw<<<12288, 256, 0, stream>>>(hidden, Wq, Wk, Wv, Wo, xb, wt);
    gemm_8ph<3><<<dim3(64, 12), 512, 0, stream>>>(xb, wt, qb, kb, vT, nullptr);
    attn_mfma<<<NBLK * NHEAD * BATCH, 256, 0, stream>>>(qb, kb, vT, table, xb);
    gemm_8ph<1><<<dim3(64, 4), 512, 0, stream>>>(xb, wt + 3 * wElems,
                                                 nullptr, nullptr, nullptr, out);
}

// Round 15
// 228.494 us; speedup vs baseline: 1.0758x; 1.0758x over previous
//
#include <hip/hip_runtime.h>
#include <hip/hip_bf16.h>

// LocalAttention (T5-style blocked local attention).
// T=4096, B=4, C=1024, H=16, D=64, L=128, NB=32, window = 3 blocks = 384 keys.
//
// Round 14: r13 with the compile fix (aq[mi] -> aq[mi][ks] in the swapped
// mfma). Swapped-QK^T softmax: mfma(K,Q) puts 4 consecutive kk per lane ->
// packed cvt_pk_bf16 + ds_write_b64 P-writes, per-lane scalar l with one
// deferred shfl reduce. Pl layout unchanged -> PV path identical to r10.
// GEMMs / conv unchanged from r12.

#define T_LEN 4096
#define BATCH 4
#define CDIM 1024
#define NHEAD 16
#define HDIM 64
#define BLK 128
#define NBLK 32
#define LOG2E 1.4426950408889634f

typedef __attribute__((ext_vector_type(8))) short bf16x8;
typedef __attribute__((ext_vector_type(4))) float f32x4;

__device__ __forceinline__ unsigned short f2b(float f) {
    __hip_bfloat16 h = __float2bfloat16(f);
    return *reinterpret_cast<unsigned short*>(&h);
}
__device__ __forceinline__ float exp2_fast(float x) {
    float r;
    asm("v_exp_f32 %0, %1" : "=v"(r) : "v"(x));
    return r;
}
__device__ __forceinline__ unsigned int cvt_pk_bf16(float a, float b) {
    unsigned int r;
    asm("v_cvt_pk_bf16_f32 %0, %1, %2" : "=v"(r) : "v"(a), "v"(b));
    return r;   // low16 = bf16(a), high16 = bf16(b)
}
__device__ __forceinline__ void gl_lds16(const void* g, void* l) {
    __builtin_amdgcn_global_load_lds(
        (const __attribute__((address_space(1))) unsigned int*)g,
        (__attribute__((address_space(3))) unsigned int*)l, 16, 0, 0);
}

// ---- merged conversion kernel ----
__global__ __launch_bounds__(256) void conv_xw(
    const float* __restrict__ hidden,
    const float* __restrict__ W0, const float* __restrict__ W1,
    const float* __restrict__ W2, const float* __restrict__ W3,
    unsigned short* __restrict__ xb, unsigned short* __restrict__ wt)
{
    __shared__ float tile[32][33];
    const int bid = blockIdx.x;
    if (bid < 8192) {
        int chunk = bid * 256 + threadIdx.x;
        int c8 = chunk & 127;
        int rem = chunk >> 7;                          // = t*4 + b
        int b = rem & 3;
        int t = rem >> 2;
        const float* src = hidden + ((size_t)rem << 10) + c8 * 8;
        float4 v0 = *(const float4*)src;
        float4 v1 = *(const float4*)(src + 4);
        bf16x8 o;
        o[0] = (short)f2b(v0.x); o[1] = (short)f2b(v0.y);
        o[2] = (short)f2b(v0.z); o[3] = (short)f2b(v0.w);
        o[4] = (short)f2b(v1.x); o[5] = (short)f2b(v1.y);
        o[6] = (short)f2b(v1.z); o[7] = (short)f2b(v1.w);
        *(bf16x8*)&xb[((size_t)(b * T_LEN + t) << 10) + c8 * 8] = o;
    } else {
        const int id = bid - 8192;                     // 0..4095
        const int z = id >> 10;
        const int rem = id & 1023;
        const int k0 = (rem & 31) * 32;
        const int n0 = (rem >> 5) * 32;
        const float* W = (z == 0) ? W0 : (z == 1) ? W1 : (z == 2) ? W2 : W3;
        const float scale = (z == 0) ? 0.125f * LOG2E : 1.0f;
        unsigned short* hi = wt + (size_t)z * (CDIM * CDIM);
        const int r = threadIdx.x >> 5;   // 0..7
        const int c = threadIdx.x & 31;
#pragma unroll
        for (int i = 0; i < 4; ++i)
            tile[r + i * 8][c] = W[(size_t)(k0 + r + i * 8) * CDIM + n0 + c] * scale;
        __syncthreads();
#pragma unroll
        for (int i = 0; i < 4; ++i) {
            int nn = r + i * 8;
            hi[(size_t)(n0 + nn) * CDIM + k0 + c] = f2b(tile[c][nn]);
        }
    }
}

// ================= 8-phase 256x256 GEMM (bf16 MFMA) =================
// MODE 1: out_proj. MODE 3: fused qkv (q/k path + operand-swapped v^T path).

#define STAGE(pb, tau, half, isB) do {                                         \
    const unsigned short* _gb = (isB) ? Bg : Ag;                               \
    const int _bo = (pb) * 32768 + (isB) * 16384 + (half) * 8192;              \
    gl_lds16(_gb + (size_t)((half) * 128 + sr) * 1024 + (tau) * 64,            \
             (short*)lds + _bo + ldsW);                                        \
    gl_lds16(_gb + (size_t)((half) * 128 + 64 + sr) * 1024 + (tau) * 64,       \
             (short*)lds + _bo + 4096 + ldsW);                                 \
} while (0)

#define LDB(p) do {                                                            \
    _Pragma("unroll") for (int nr = 0; nr < 4; ++nr) {                         \
        int _row = wc * 64 + nr * 16 + li;                                     \
        _Pragma("unroll") for (int ks = 0; ks < 2; ++ks)                       \
            bkf[nr][ks] = *(const bf16x8*)(ldsc + (p) * 65536 + 32768 +        \
                ((_row * 128 + ks * 64 + g * 16) ^ swz));                      \
    } } while (0)

#define LDA(p, q) do {                                                         \
    _Pragma("unroll") for (int dm = 0; dm < 2; ++dm) {                         \
        int _row = wr * 128 + ((q) * 2 + dm) * 16 + li;                        \
        _Pragma("unroll") for (int ks = 0; ks < 2; ++ks)                       \
            af[dm][ks] = *(const bf16x8*)(ldsc + (p) * 65536 +                 \
                ((_row * 128 + ks * 64 + g * 16) ^ swz));                      \
    } } while (0)

#define MM(q) do {                                                             \
    _Pragma("unroll") for (int dm = 0; dm < 2; ++dm)                           \
    _Pragma("unroll") for (int nr = 0; nr < 4; ++nr) {                         \
        acc[(q)*2+dm][nr] = __builtin_amdgcn_mfma_f32_16x16x32_bf16(           \
            af[dm][0], bkf[nr][0], acc[(q)*2+dm][nr], 0, 0, 0);                \
        acc[(q)*2+dm][nr] = __builtin_amdgcn_mfma_f32_16x16x32_bf16(           \
            af[dm][1], bkf[nr][1], acc[(q)*2+dm][nr], 0, 0, 0);                \
    } } while (0)

#define MID() do {                                                             \
    __builtin_amdgcn_s_barrier();                                              \
    asm volatile("s_waitcnt lgkmcnt(0)" ::: "memory");                         \
    __builtin_amdgcn_sched_barrier(0);                                         \
    __builtin_amdgcn_s_setprio(1);                                             \
} while (0)

#define TAIL() do {                                                            \
    __builtin_amdgcn_s_setprio(0);                                             \
    __builtin_amdgcn_sched_barrier(0);                                         \
    __builtin_amdgcn_s_barrier();                                              \
} while (0)

template<int MODE>
__global__ __launch_bounds__(512, 1) void gemm_8ph(
    const unsigned short* __restrict__ Am,
    const unsigned short* __restrict__ Bm,
    unsigned short* __restrict__ qb, unsigned short* __restrict__ kb,
    unsigned short* __restrict__ vT, float* __restrict__ fout)
{
    __shared__ short lds[65536];   // 128 KB: [buf:2][A 256x64 | B 256x64]

    const int tid = threadIdx.x;
    const int w = tid >> 6, lane = tid & 63;
    const int g = lane >> 4, li = lane & 15;
    const int wr = w >> 2, wc = w & 3;           // 2 x 4 wave grid

    const int L = blockIdx.y * gridDim.x + blockIdx.x;
    bool isV = false;
    int m0, n0;
    const unsigned short *Abase, *Bbase;
    if (MODE == 3) {
        const int wrk = (L & 7) * 96 + (L >> 3);   // 768 blocks, bijective
        const int x = wrk / 12, y = wrk % 12;
        isV = (y >= 8);
        if (isV) {
            Abase = Bm + 2 * (size_t)(CDIM * CDIM);   // WvT
            Bbase = Am;                               // xb
            m0 = (y - 8) * 256;                       // over M=1024
            n0 = x * 256;                             // over N=16384
        } else {
            Abase = Am;                               // xb
            Bbase = Bm;                               // WqT|WkT
            m0 = x * 256;
            n0 = y * 256;                             // over N=2048
        }
    } else {
        const int wrk = (L & 7) * 32 + (L >> 3);   // 256 blocks, bijective
        const int x = wrk >> 2, y = wrk & 3;
        Abase = Am; Bbase = Bm;
        m0 = x * 256;
        n0 = y * 256;
    }

    const int sr = tid >> 3;                       // 0..63
    const int cbs = ((tid & 7) * 16) ^ ((sr & 7) << 4);
    const int ldsW = w * 512;                      // shorts (wave-uniform)
    const unsigned short* Ag = Abase + (size_t)m0 * 1024 + (cbs >> 1);
    const unsigned short* Bg = Bbase + (size_t)n0 * 1024 + (cbs >> 1);

    const char* ldsc = (const char*)lds;
    const int swz = (li & 7) << 4;

    f32x4 acc[8][4];
#pragma unroll
    for (int a = 0; a < 8; ++a)
#pragma unroll
        for (int b = 0; b < 4; ++b) acc[a][b] = (f32x4){0.f, 0.f, 0.f, 0.f};

    bf16x8 bkf[4][2];
    bf16x8 af[2][2];

    // prologue: tile0 fully + B halves of tile1; drain tile0 (4 loads left)
    STAGE(0, 0, 0, 0); STAGE(0, 0, 1, 0);
    STAGE(0, 0, 0, 1); STAGE(0, 0, 1, 1);
    STAGE(1, 1, 0, 1); STAGE(1, 1, 1, 1);
    asm volatile("s_waitcnt vmcnt(4)" ::: "memory");
    __builtin_amdgcn_s_barrier();

#pragma unroll 1
    for (int i = 0; i < 8; ++i) {
        const int o = 2 * i + 1, e2 = 2 * i + 2, o2 = 2 * i + 3;
        const bool pf = (i < 7);
        // ---- even tile (buf0) ----
        LDB(0); LDA(0, 0); STAGE(1, o, 0, 0); MID(); MM(0); TAIL();
        LDA(0, 1); STAGE(1, o, 1, 0); MID(); MM(1); TAIL();
        LDA(0, 2); if (pf) STAGE(0, e2, 0, 1); MID(); MM(2); TAIL();
        LDA(0, 3); if (pf) STAGE(0, e2, 1, 1); MID(); MM(3);
        __builtin_amdgcn_s_setprio(0);
        __builtin_amdgcn_sched_barrier(0);
        if (pf) asm volatile("s_waitcnt vmcnt(4)" ::: "memory");
        else    asm volatile("s_waitcnt vmcnt(0)" ::: "memory");
        __builtin_amdgcn_s_barrier();
        // ---- odd tile (buf1) ----
        LDB(1); LDA(1, 0); if (pf) STAGE(0, e2, 0, 0); MID(); MM(0); TAIL();
        LDA(1, 1); if (pf) STAGE(0, e2, 1, 0); MID(); MM(1); TAIL();
        LDA(1, 2); if (pf) STAGE(1, o2, 0, 1); MID(); MM(2); TAIL();
        LDA(1, 3); if (pf) STAGE(1, o2, 1, 1); MID(); MM(3);
        __builtin_amdgcn_s_setprio(0);
        __builtin_amdgcn_sched_barrier(0);
        if (pf) asm volatile("s_waitcnt vmcnt(4)" ::: "memory");
        else    asm volatile("s_waitcnt vmcnt(0)" ::: "memory");
        __builtin_amdgcn_s_barrier();
    }

    if (MODE == 3 && !isV) {
        const int nA = n0 + wc * 64;
        const int hh = (nA & 1023) >> 6;
        unsigned short* ob = ((nA >> 10) == 0) ? qb : kb;
#pragma unroll
        for (int mr = 0; mr < 8; ++mr)
#pragma unroll
            for (int reg = 0; reg < 4; ++reg) {
                int m = m0 + wr * 128 + mr * 16 + g * 4 + reg;
                size_t ro = ((size_t)((m >> 12) * NHEAD + hh) * T_LEN + (m & 4095)) * HDIM;
#pragma unroll
                for (int nr = 0; nr < 4; ++nr)
                    ob[ro + nr * 16 + li] = f2b(acc[mr][nr][reg]);
            }
    } else if (MODE == 3) {
        // v^T: m = Wv-row = h*64+d; n = xb-row = b*4096+t
#pragma unroll
        for (int mr = 0; mr < 8; ++mr)
#pragma unroll
            for (int reg = 0; reg < 4; ++reg) {
                int m = m0 + wr * 128 + mr * 16 + g * 4 + reg;
#pragma unroll
                for (int nr = 0; nr < 4; ++nr) {
                    int nn = n0 + wc * 64 + nr * 16 + li;
                    vT[((size_t)((nn >> 12) * 1024 + m) << 12) + (nn & 4095)] =
                        f2b(acc[mr][nr][reg]);
                }
            }
    } else {
#pragma unroll
        for (int mr = 0; mr < 8; ++mr)
#pragma unroll
            for (int reg = 0; reg < 4; ++reg) {
                int m = m0 + wr * 128 + mr * 16 + g * 4 + reg;
                float* orow = fout + ((size_t)(m & 4095) * BATCH + (m >> 12)) * CDIM
                              + n0 + wc * 64;
#pragma unroll
                for (int nr = 0; nr < 4; ++nr)
                    orow[nr * 16 + li] = acc[mr][nr][reg];
            }
    }
}

// ---------------- relative position bucket (== reference fp32 log formula) ----
__device__ __forceinline__ int rel_bucket(int rel) {
    int rb = (rel > 0) ? 16 : 0;
    int rp = abs(rel);
    int bu;
    if (rp < 8) bu = rp;
    else if (rp < 12) bu = 8;
    else if (rp < 16) bu = 9;
    else if (rp < 23) bu = 10;
    else if (rp < 32) bu = 11;
    else if (rp < 46) bu = 12;
    else if (rp < 64) bu = 13;
    else if (rp < 91) bu = 14;
    else bu = 15;
    return rb + bu;
}

// ---------------- MFMA attention: swapped-QK^T, packed P, LDS-staged K/V ----
// grid 2048 (XCD-swizzled), 256 threads = 4 waves; wave w owns q-rows
// [32w,32w+32). S^T = mfma(K,Q): lane holds kk = ni*16+g*4+reg (4 consecutive)
// for q-col = mi*16+li -> cvt_pk + ds_write_b64 packed P, per-lane scalar l.
// Pl layout [q][kk] unchanged -> PV path identical to r10.
#define PL_STR 72

__global__ __launch_bounds__(256) void attn_mfma(
    const unsigned short* __restrict__ qb, const unsigned short* __restrict__ kb,
    const unsigned short* __restrict__ vT, const float* __restrict__ table,
    unsigned short* __restrict__ ao)
{
    const int bid = blockIdx.x;
    const int lb = (bid & 7) * 256 + (bid >> 3);
    const int n = lb & 31;
    const int h = (lb >> 5) & 15;
    const int b = lb >> 9;
    const int tid = threadIdx.x;
    const int w = tid >> 6;
    const int lane = tid & 63;
    const int g = lane >> 4;
    const int li = lane & 15;

    __shared__ short kvS[2][2][4096];   // [buf][K|V][64x64], 32 KB
    __shared__ short Pl[4][32 * PL_STR];
    __shared__ float ldsb[512];

    for (int i = tid; i < 512; i += 256)
        ldsb[i] = table[rel_bucket(i - 255) * NHEAD + h] * LOG2E;

    const unsigned short* qBase =
        qb + (((size_t)b * NHEAD + h) * T_LEN + (size_t)n * BLK) * HDIM;
    const unsigned short* kBase = kb + ((size_t)b * NHEAD + h) * T_LEN * HDIM;
    const unsigned short* vTBase = vT + ((size_t)b * NHEAD + h) * (size_t)HDIM * T_LEN;

    const int srow = lane >> 3;                               // 0..7
    const int scol = (((lane & 7) * 16) ^ (srow << 4)) >> 1;  // swizzled, shorts
    const int swz = (li & 7) << 4;                            // read-side XOR

#define STAGEKV(pb, tk0) do {                                                  \
    _Pragma("unroll") for (int u = 0; u < 2; ++u) {                            \
        int _r = u * 32 + w * 8 + srow;                                        \
        gl_lds16(kBase + (size_t)((tk0) + _r) * HDIM + scol,                   \
                 &kvS[pb][0][u * 2048 + w * 512]);                             \
        gl_lds16(vTBase + (size_t)_r * T_LEN + (tk0) + scol,                   \
                 &kvS[pb][1][u * 2048 + w * 512]);                             \
    } } while (0)

    bf16x8 aq[2][2];
#pragma unroll
    for (int mi = 0; mi < 2; ++mi)
#pragma unroll
        for (int ks = 0; ks < 2; ++ks)
            aq[mi][ks] = *(const bf16x8*)(qBase +
                (size_t)(w * 32 + mi * 16 + li) * HDIM + ks * 32 + g * 8);

    f32x4 oacc[2][4];
    float lp[2] = {0.f, 0.f};
#pragma unroll
    for (int mi = 0; mi < 2; ++mi)
#pragma unroll
        for (int dn = 0; dn < 4; ++dn)
            oacc[mi][dn] = (f32x4){0.f, 0.f, 0.f, 0.f};

    const int tkbase = (n - 1) * BLK;
    if (tkbase >= 0) STAGEKV(0, tkbase);
    __syncthreads();   // tile0 staged (also covers ldsb)

#pragma unroll
    for (int kt = 0; kt < 6; ++kt) {
        const int tk0 = tkbase + kt * 64;
        const bool inb = (tk0 >= 0) && (tk0 < T_LEN);   // block-uniform
        const int cur = kt & 1;

        // issue next tile's stage (drains into end-of-iter barrier)
        if (kt < 5) {
            const int tkn = tk0 + 64;
            if (tkn >= 0 && tkn < T_LEN) STAGEKV(cur ^ 1, tkn);
        }

        const char* kbufC = (const char*)kvS[cur][0];
        const char* vbufC = (const char*)kvS[cur][1];

        // ---- S^T = K Q^T (log2 domain; swapped operands) ----
        f32x4 sacc[2][4];
#pragma unroll
        for (int mi = 0; mi < 2; ++mi)
#pragma unroll
            for (int ni = 0; ni < 4; ++ni)
                sacc[mi][ni] = (f32x4){0.f, 0.f, 0.f, 0.f};
        if (inb) {
            __builtin_amdgcn_s_setprio(1);
#pragma unroll
            for (int ks = 0; ks < 2; ++ks) {
                bf16x8 bk[4];
#pragma unroll
                for (int ni = 0; ni < 4; ++ni)
                    bk[ni] = *(const bf16x8*)(kbufC +
                        ((ni * 16 + li) * 128 + ((ks * 64 + g * 16) ^ swz)));
#pragma unroll
                for (int mi = 0; mi < 2; ++mi)
#pragma unroll
                    for (int ni = 0; ni < 4; ++ni)
                        sacc[mi][ni] = __builtin_amdgcn_mfma_f32_16x16x32_bf16(
                            bk[ni], aq[mi][ks], sacc[mi][ni], 0, 0, 0);
            }
            __builtin_amdgcn_s_setprio(0);
        }

        // ---- p = exp2(s^T + bias'); packed bf16 pairs -> Pl; scalar l ----
        // lane: q = w*32 + mi*16 + li ; kk = kt*64 + ni*16 + g*4 + reg
#pragma unroll
        for (int mi = 0; mi < 2; ++mi) {
            const int idxC = kt * 64 + g * 4 - (w * 32 + mi * 16 + li) + 127;
            float p[4][4];   // [ni][reg]
#pragma unroll
            for (int reg = 0; reg < 4; ++reg) {
                const float* lbp = ldsb + idxC + reg;
                p[0][reg] = exp2_fast(sacc[mi][0][reg] + lbp[0]);
                p[1][reg] = exp2_fast(sacc[mi][1][reg] + lbp[16]);
                p[2][reg] = exp2_fast(sacc[mi][2][reg] + lbp[32]);
                p[3][reg] = exp2_fast(sacc[mi][3][reg] + lbp[48]);
                lp[mi] += (p[0][reg] + p[1][reg]) + (p[2][reg] + p[3][reg]);
            }
#pragma unroll
            for (int ni = 0; ni < 4; ++ni) {
                unsigned int lo = cvt_pk_bf16(p[ni][0], p[ni][1]);
                unsigned int hi = cvt_pk_bf16(p[ni][2], p[ni][3]);
                *(uint2*)&Pl[w][(mi * 16 + li) * PL_STR + ni * 16 + g * 4] =
                    make_uint2(lo, hi);
            }
        }

        // ---- O += P V (V frags from LDS; skip OOB tiles: V == 0) ----
        if (inb) {
            __builtin_amdgcn_s_setprio(1);
#pragma unroll
            for (int ks = 0; ks < 2; ++ks) {
                bf16x8 ap[2], bv[4];
#pragma unroll
                for (int mi = 0; mi < 2; ++mi)
                    ap[mi] = *(bf16x8*)&Pl[w][(mi * 16 + li) * PL_STR + ks * 32 + g * 8];
#pragma unroll
                for (int dn = 0; dn < 4; ++dn)
                    bv[dn] = *(const bf16x8*)(vbufC +
                        ((dn * 16 + li) * 128 + ((ks * 64 + g * 16) ^ swz)));
#pragma unroll
                for (int mi = 0; mi < 2; ++mi)
#pragma unroll
                    for (int dn = 0; dn < 4; ++dn)
                        oacc[mi][dn] = __builtin_amdgcn_mfma_f32_16x16x32_bf16(
                            ap[mi], bv[dn], oacc[mi][dn], 0, 0, 0);
            }
            __builtin_amdgcn_s_setprio(0);
        }

        __syncthreads();   // next-tile stage drained; buf[cur] free for reuse
    }

    // ---- deferred l-reduce (across g) + redistribute + write out ----
#pragma unroll
    for (int mi = 0; mi < 2; ++mi) {
        float l = lp[mi];
        l += __shfl_xor(l, 16);
        l += __shfl_xor(l, 32);   // now lane holds full l for q = mi*16+li
#pragma unroll
        for (int reg = 0; reg < 4; ++reg) {
            float inv = 1.f / __shfl(l, g * 4 + reg);  // l of row g*4+reg
            int t = n * BLK + w * 32 + mi * 16 + g * 4 + reg;
            unsigned short* orow = ao + ((size_t)b * T_LEN + t) * CDIM + h * HDIM;
#pragma unroll
            for (int dn = 0; dn < 4; ++dn)
                orow[dn * 16 + li] = f2b(oacc[mi][dn][reg] * inv);
        }
    }
#undef STAGEKV
}

extern "C" void kernel_launch(void* const* d_in, const int* in_sizes, int n_in,
                              void* d_out, int out_size, void* d_ws, size_t ws_size,
                              hipStream_t stream) {
    const float* hidden = (const float*)d_in[0];
    const float* Wq = (const float*)d_in[1];
    const float* Wk = (const float*)d_in[2];
    const float* Wv = (const float*)d_in[3];
    const float* Wo = (const float*)d_in[4];
    const float* table = (const float*)d_in[5];
    float* out = (float*)d_out;

    const size_t qkvElems = (size_t)BATCH * NHEAD * T_LEN * HDIM;   // 16.78M
    const size_t wElems = (size_t)CDIM * CDIM;                      // 1.05M
    const size_t needed = (4 * qkvElems + 4 * wElems) * 2;          // ~136 MiB
    if (ws_size < needed) return;

    unsigned short* qb = (unsigned short*)d_ws;
    unsigned short* kb = qb + qkvElems;
    unsigned short* vT = kb + qkvElems;     // [b][h][d][t]
    unsigned short* xb = vT + qkvElems;     // reused as ao after proj
    unsigned short* wt = xb + qkvElems;     // [WqT|WkT|WvT|WoT], each [1024][1024]

    conv_xw<<<12288, 256, 0, stream>>>(hidden, Wq, Wk, Wv, Wo, xb, wt);
    gemm_8ph<3><<<dim3(64, 12), 512, 0, stream>>>(xb, wt, qb, kb, vT, nullptr);
    attn_mfma<<<NBLK * NHEAD * BATCH, 256, 0, stream>>>(qb, kb, vT, table, xb);
    gemm_8ph<1><<<dim3(64, 4), 512, 0, stream>>>(xb, wt + 3 * wElems,
                                                 nullptr, nullptr, nullptr, out);
}

// Round 16
// 227.476 us; speedup vs baseline: 1.0806x; 1.0045x over previous
//
#include <hip/hip_runtime.h>
#include <hip/hip_bf16.h>

// LocalAttention (T5-style blocked local attention).
// T=4096, B=4, C=1024, H=16, D=64, L=128, NB=32, window = 3 blocks = 384 keys.
//
// Round 15: gemm_8ph -> 2 phases per K-tile (was 4). r14 PMC: gemm<3> 112us,
// MfmaUtil 40%; per-CU accounting (MFMA 12us, LDS ~31us, HBM 15us) leaves
// ~50% as barrier/lgkm sync tax (16 barriers/K-tile-pair at 8 iters, 2
// waves/SIMD lockstep). Merge halves the sync count; stage issue order and
// vmcnt(4/0) drain points unchanged (same liveness proof as r5). 4 extra
// A-frags (+16 VGPR, free at 1 block/CU). attn (swapped-QK^T r14) unchanged.

#define T_LEN 4096
#define BATCH 4
#define CDIM 1024
#define NHEAD 16
#define HDIM 64
#define BLK 128
#define NBLK 32
#define LOG2E 1.4426950408889634f

typedef __attribute__((ext_vector_type(8))) short bf16x8;
typedef __attribute__((ext_vector_type(4))) float f32x4;

__device__ __forceinline__ unsigned short f2b(float f) {
    __hip_bfloat16 h = __float2bfloat16(f);
    return *reinterpret_cast<unsigned short*>(&h);
}
__device__ __forceinline__ float exp2_fast(float x) {
    float r;
    asm("v_exp_f32 %0, %1" : "=v"(r) : "v"(x));
    return r;
}
__device__ __forceinline__ unsigned int cvt_pk_bf16(float a, float b) {
    unsigned int r;
    asm("v_cvt_pk_bf16_f32 %0, %1, %2" : "=v"(r) : "v"(a), "v"(b));
    return r;   // low16 = bf16(a), high16 = bf16(b)
}
__device__ __forceinline__ void gl_lds16(const void* g, void* l) {
    __builtin_amdgcn_global_load_lds(
        (const __attribute__((address_space(1))) unsigned int*)g,
        (__attribute__((address_space(3))) unsigned int*)l, 16, 0, 0);
}

// ---- merged conversion kernel ----
__global__ __launch_bounds__(256) void conv_xw(
    const float* __restrict__ hidden,
    const float* __restrict__ W0, const float* __restrict__ W1,
    const float* __restrict__ W2, const float* __restrict__ W3,
    unsigned short* __restrict__ xb, unsigned short* __restrict__ wt)
{
    __shared__ float tile[32][33];
    const int bid = blockIdx.x;
    if (bid < 8192) {
        int chunk = bid * 256 + threadIdx.x;
        int c8 = chunk & 127;
        int rem = chunk >> 7;                          // = t*4 + b
        int b = rem & 3;
        int t = rem >> 2;
        const float* src = hidden + ((size_t)rem << 10) + c8 * 8;
        float4 v0 = *(const float4*)src;
        float4 v1 = *(const float4*)(src + 4);
        bf16x8 o;
        o[0] = (short)f2b(v0.x); o[1] = (short)f2b(v0.y);
        o[2] = (short)f2b(v0.z); o[3] = (short)f2b(v0.w);
        o[4] = (short)f2b(v1.x); o[5] = (short)f2b(v1.y);
        o[6] = (short)f2b(v1.z); o[7] = (short)f2b(v1.w);
        *(bf16x8*)&xb[((size_t)(b * T_LEN + t) << 10) + c8 * 8] = o;
    } else {
        const int id = bid - 8192;                     // 0..4095
        const int z = id >> 10;
        const int rem = id & 1023;
        const int k0 = (rem & 31) * 32;
        const int n0 = (rem >> 5) * 32;
        const float* W = (z == 0) ? W0 : (z == 1) ? W1 : (z == 2) ? W2 : W3;
        const float scale = (z == 0) ? 0.125f * LOG2E : 1.0f;
        unsigned short* hi = wt + (size_t)z * (CDIM * CDIM);
        const int r = threadIdx.x >> 5;   // 0..7
        const int c = threadIdx.x & 31;
#pragma unroll
        for (int i = 0; i < 4; ++i)
            tile[r + i * 8][c] = W[(size_t)(k0 + r + i * 8) * CDIM + n0 + c] * scale;
        __syncthreads();
#pragma unroll
        for (int i = 0; i < 4; ++i) {
            int nn = r + i * 8;
            hi[(size_t)(n0 + nn) * CDIM + k0 + c] = f2b(tile[c][nn]);
        }
    }
}

// ================= 2-phase 256x256 GEMM (bf16 MFMA) =================
// MODE 1: out_proj. MODE 3: fused qkv (q/k path + operand-swapped v^T path).

#define STAGE(pb, tau, half, isB) do {                                         \
    const unsigned short* _gb = (isB) ? Bg : Ag;                               \
    const int _bo = (pb) * 32768 + (isB) * 16384 + (half) * 8192;              \
    gl_lds16(_gb + (size_t)((half) * 128 + sr) * 1024 + (tau) * 64,            \
             (short*)lds + _bo + ldsW);                                        \
    gl_lds16(_gb + (size_t)((half) * 128 + 64 + sr) * 1024 + (tau) * 64,       \
             (short*)lds + _bo + 4096 + ldsW);                                 \
} while (0)

#define LDB(p) do {                                                            \
    _Pragma("unroll") for (int nr = 0; nr < 4; ++nr) {                         \
        int _row = wc * 64 + nr * 16 + li;                                     \
        _Pragma("unroll") for (int ks = 0; ks < 2; ++ks)                       \
            bkf[nr][ks] = *(const bf16x8*)(ldsc + (p) * 65536 + 32768 +        \
                ((_row * 128 + ks * 64 + g * 16) ^ swz));                      \
    } } while (0)

#define LDA(p, q, s) do {                                                      \
    _Pragma("unroll") for (int dm = 0; dm < 2; ++dm) {                         \
        int _row = wr * 128 + ((q) * 2 + dm) * 16 + li;                        \
        _Pragma("unroll") for (int ks = 0; ks < 2; ++ks)                       \
            af[s][dm][ks] = *(const bf16x8*)(ldsc + (p) * 65536 +              \
                ((_row * 128 + ks * 64 + g * 16) ^ swz));                      \
    } } while (0)

#define MM(q, s) do {                                                          \
    _Pragma("unroll") for (int dm = 0; dm < 2; ++dm)                           \
    _Pragma("unroll") for (int nr = 0; nr < 4; ++nr) {                         \
        acc[(q)*2+dm][nr] = __builtin_amdgcn_mfma_f32_16x16x32_bf16(           \
            af[s][dm][0], bkf[nr][0], acc[(q)*2+dm][nr], 0, 0, 0);             \
        acc[(q)*2+dm][nr] = __builtin_amdgcn_mfma_f32_16x16x32_bf16(           \
            af[s][dm][1], bkf[nr][1], acc[(q)*2+dm][nr], 0, 0, 0);             \
    } } while (0)

#define MID() do {                                                             \
    __builtin_amdgcn_s_barrier();                                              \
    asm volatile("s_waitcnt lgkmcnt(0)" ::: "memory");                         \
    __builtin_amdgcn_sched_barrier(0);                                         \
    __builtin_amdgcn_s_setprio(1);                                             \
} while (0)

#define TAIL() do {                                                            \
    __builtin_amdgcn_s_setprio(0);                                             \
    __builtin_amdgcn_sched_barrier(0);                                         \
    __builtin_amdgcn_s_barrier();                                              \
} while (0)

template<int MODE>
__global__ __launch_bounds__(512, 1) void gemm_8ph(
    const unsigned short* __restrict__ Am,
    const unsigned short* __restrict__ Bm,
    unsigned short* __restrict__ qb, unsigned short* __restrict__ kb,
    unsigned short* __restrict__ vT, float* __restrict__ fout)
{
    __shared__ short lds[65536];   // 128 KB: [buf:2][A 256x64 | B 256x64]

    const int tid = threadIdx.x;
    const int w = tid >> 6, lane = tid & 63;
    const int g = lane >> 4, li = lane & 15;
    const int wr = w >> 2, wc = w & 3;           // 2 x 4 wave grid

    const int L = blockIdx.y * gridDim.x + blockIdx.x;
    bool isV = false;
    int m0, n0;
    const unsigned short *Abase, *Bbase;
    if (MODE == 3) {
        const int wrk = (L & 7) * 96 + (L >> 3);   // 768 blocks, bijective
        const int x = wrk / 12, y = wrk % 12;
        isV = (y >= 8);
        if (isV) {
            Abase = Bm + 2 * (size_t)(CDIM * CDIM);   // WvT
            Bbase = Am;                               // xb
            m0 = (y - 8) * 256;                       // over M=1024
            n0 = x * 256;                             // over N=16384
        } else {
            Abase = Am;                               // xb
            Bbase = Bm;                               // WqT|WkT
            m0 = x * 256;
            n0 = y * 256;                             // over N=2048
        }
    } else {
        const int wrk = (L & 7) * 32 + (L >> 3);   // 256 blocks, bijective
        const int x = wrk >> 2, y = wrk & 3;
        Abase = Am; Bbase = Bm;
        m0 = x * 256;
        n0 = y * 256;
    }

    const int sr = tid >> 3;                       // 0..63
    const int cbs = ((tid & 7) * 16) ^ ((sr & 7) << 4);
    const int ldsW = w * 512;                      // shorts (wave-uniform)
    const unsigned short* Ag = Abase + (size_t)m0 * 1024 + (cbs >> 1);
    const unsigned short* Bg = Bbase + (size_t)n0 * 1024 + (cbs >> 1);

    const char* ldsc = (const char*)lds;
    const int swz = (li & 7) << 4;

    f32x4 acc[8][4];
#pragma unroll
    for (int a = 0; a < 8; ++a)
#pragma unroll
        for (int b = 0; b < 4; ++b) acc[a][b] = (f32x4){0.f, 0.f, 0.f, 0.f};

    bf16x8 bkf[4][2];
    bf16x8 af[2][2][2];   // [quadrant slot][dm][ks]

    // prologue: tile0 fully + B halves of tile1; drain tile0 (4 loads left)
    STAGE(0, 0, 0, 0); STAGE(0, 0, 1, 0);
    STAGE(0, 0, 0, 1); STAGE(0, 0, 1, 1);
    STAGE(1, 1, 0, 1); STAGE(1, 1, 1, 1);
    asm volatile("s_waitcnt vmcnt(4)" ::: "memory");
    __builtin_amdgcn_s_barrier();

#pragma unroll 1
    for (int i = 0; i < 8; ++i) {
        const int o = 2 * i + 1, e2 = 2 * i + 2, o2 = 2 * i + 3;
        const bool pf = (i < 7);
        // ---- even tile (buf0), 2 phases ----
        LDB(0); LDA(0, 0, 0); LDA(0, 1, 1);
        STAGE(1, o, 0, 0); STAGE(1, o, 1, 0);
        MID(); MM(0, 0); MM(1, 1); TAIL();
        LDA(0, 2, 0); LDA(0, 3, 1);
        if (pf) { STAGE(0, e2, 0, 1); STAGE(0, e2, 1, 1); }
        MID(); MM(2, 0); MM(3, 1);
        __builtin_amdgcn_s_setprio(0);
        __builtin_amdgcn_sched_barrier(0);
        if (pf) asm volatile("s_waitcnt vmcnt(4)" ::: "memory");
        else    asm volatile("s_waitcnt vmcnt(0)" ::: "memory");
        __builtin_amdgcn_s_barrier();
        // ---- odd tile (buf1), 2 phases ----
        LDB(1); LDA(1, 0, 0); LDA(1, 1, 1);
        if (pf) { STAGE(0, e2, 0, 0); STAGE(0, e2, 1, 0); }
        MID(); MM(0, 0); MM(1, 1); TAIL();
        LDA(1, 2, 0); LDA(1, 3, 1);
        if (pf) { STAGE(1, o2, 0, 1); STAGE(1, o2, 1, 1); }
        MID(); MM(2, 0); MM(3, 1);
        __builtin_amdgcn_s_setprio(0);
        __builtin_amdgcn_sched_barrier(0);
        if (pf) asm volatile("s_waitcnt vmcnt(4)" ::: "memory");
        else    asm volatile("s_waitcnt vmcnt(0)" ::: "memory");
        __builtin_amdgcn_s_barrier();
    }

    if (MODE == 3 && !isV) {
        const int nA = n0 + wc * 64;
        const int hh = (nA & 1023) >> 6;
        unsigned short* ob = ((nA >> 10) == 0) ? qb : kb;
#pragma unroll
        for (int mr = 0; mr < 8; ++mr)
#pragma unroll
            for (int reg = 0; reg < 4; ++reg) {
                int m = m0 + wr * 128 + mr * 16 + g * 4 + reg;
                size_t ro = ((size_t)((m >> 12) * NHEAD + hh) * T_LEN + (m & 4095)) * HDIM;
#pragma unroll
                for (int nr = 0; nr < 4; ++nr)
                    ob[ro + nr * 16 + li] = f2b(acc[mr][nr][reg]);
            }
    } else if (MODE == 3) {
        // v^T: m = Wv-row = h*64+d; n = xb-row = b*4096+t
#pragma unroll
        for (int mr = 0; mr < 8; ++mr)
#pragma unroll
            for (int reg = 0; reg < 4; ++reg) {
                int m = m0 + wr * 128 + mr * 16 + g * 4 + reg;
#pragma unroll
                for (int nr = 0; nr < 4; ++nr) {
                    int nn = n0 + wc * 64 + nr * 16 + li;
                    vT[((size_t)((nn >> 12) * 1024 + m) << 12) + (nn & 4095)] =
                        f2b(acc[mr][nr][reg]);
                }
            }
    } else {
#pragma unroll
        for (int mr = 0; mr < 8; ++mr)
#pragma unroll
            for (int reg = 0; reg < 4; ++reg) {
                int m = m0 + wr * 128 + mr * 16 + g * 4 + reg;
                float* orow = fout + ((size_t)(m & 4095) * BATCH + (m >> 12)) * CDIM
                              + n0 + wc * 64;
#pragma unroll
                for (int nr = 0; nr < 4; ++nr)
                    orow[nr * 16 + li] = acc[mr][nr][reg];
            }
    }
}

// ---------------- relative position bucket (== reference fp32 log formula) ----
__device__ __forceinline__ int rel_bucket(int rel) {
    int rb = (rel > 0) ? 16 : 0;
    int rp = abs(rel);
    int bu;
    if (rp < 8) bu = rp;
    else if (rp < 12) bu = 8;
    else if (rp < 16) bu = 9;
    else if (rp < 23) bu = 10;
    else if (rp < 32) bu = 11;
    else if (rp < 46) bu = 12;
    else if (rp < 64) bu = 13;
    else if (rp < 91) bu = 14;
    else bu = 15;
    return rb + bu;
}

// ---------------- MFMA attention: swapped-QK^T, packed P, LDS-staged K/V ----
#define PL_STR 72

__global__ __launch_bounds__(256) void attn_mfma(
    const unsigned short* __restrict__ qb, const unsigned short* __restrict__ kb,
    const unsigned short* __restrict__ vT, const float* __restrict__ table,
    unsigned short* __restrict__ ao)
{
    const int bid = blockIdx.x;
    const int lb = (bid & 7) * 256 + (bid >> 3);
    const int n = lb & 31;
    const int h = (lb >> 5) & 15;
    const int b = lb >> 9;
    const int tid = threadIdx.x;
    const int w = tid >> 6;
    const int lane = tid & 63;
    const int g = lane >> 4;
    const int li = lane & 15;

    __shared__ short kvS[2][2][4096];   // [buf][K|V][64x64], 32 KB
    __shared__ short Pl[4][32 * PL_STR];
    __shared__ float ldsb[512];

    for (int i = tid; i < 512; i += 256)
        ldsb[i] = table[rel_bucket(i - 255) * NHEAD + h] * LOG2E;

    const unsigned short* qBase =
        qb + (((size_t)b * NHEAD + h) * T_LEN + (size_t)n * BLK) * HDIM;
    const unsigned short* kBase = kb + ((size_t)b * NHEAD + h) * T_LEN * HDIM;
    const unsigned short* vTBase = vT + ((size_t)b * NHEAD + h) * (size_t)HDIM * T_LEN;

    const int srow = lane >> 3;                               // 0..7
    const int scol = (((lane & 7) * 16) ^ (srow << 4)) >> 1;  // swizzled, shorts
    const int swz = (li & 7) << 4;                            // read-side XOR

#define STAGEKV(pb, tk0) do {                                                  \
    _Pragma("unroll") for (int u = 0; u < 2; ++u) {                            \
        int _r = u * 32 + w * 8 + srow;                                        \
        gl_lds16(kBase + (size_t)((tk0) + _r) * HDIM + scol,                   \
                 &kvS[pb][0][u * 2048 + w * 512]);                             \
        gl_lds16(vTBase + (size_t)_r * T_LEN + (tk0) + scol,                   \
                 &kvS[pb][1][u * 2048 + w * 512]);                             \
    } } while (0)

    bf16x8 aq[2][2];
#pragma unroll
    for (int mi = 0; mi < 2; ++mi)
#pragma unroll
        for (int ks = 0; ks < 2; ++ks)
            aq[mi][ks] = *(const bf16x8*)(qBase +
                (size_t)(w * 32 + mi * 16 + li) * HDIM + ks * 32 + g * 8);

    f32x4 oacc[2][4];
    float lp[2] = {0.f, 0.f};
#pragma unroll
    for (int mi = 0; mi < 2; ++mi)
#pragma unroll
        for (int dn = 0; dn < 4; ++dn)
            oacc[mi][dn] = (f32x4){0.f, 0.f, 0.f, 0.f};

    const int tkbase = (n - 1) * BLK;
    if (tkbase >= 0) STAGEKV(0, tkbase);
    __syncthreads();   // tile0 staged (also covers ldsb)

#pragma unroll
    for (int kt = 0; kt < 6; ++kt) {
        const int tk0 = tkbase + kt * 64;
        const bool inb = (tk0 >= 0) && (tk0 < T_LEN);   // block-uniform
        const int cur = kt & 1;

        // issue next tile's stage (drains into end-of-iter barrier)
        if (kt < 5) {
            const int tkn = tk0 + 64;
            if (tkn >= 0 && tkn < T_LEN) STAGEKV(cur ^ 1, tkn);
        }

        const char* kbufC = (const char*)kvS[cur][0];
        const char* vbufC = (const char*)kvS[cur][1];

        // ---- S^T = K Q^T (log2 domain; swapped operands) ----
        f32x4 sacc[2][4];
#pragma unroll
        for (int mi = 0; mi < 2; ++mi)
#pragma unroll
            for (int ni = 0; ni < 4; ++ni)
                sacc[mi][ni] = (f32x4){0.f, 0.f, 0.f, 0.f};
        if (inb) {
            __builtin_amdgcn_s_setprio(1);
#pragma unroll
            for (int ks = 0; ks < 2; ++ks) {
                bf16x8 bk[4];
#pragma unroll
                for (int ni = 0; ni < 4; ++ni)
                    bk[ni] = *(const bf16x8*)(kbufC +
                        ((ni * 16 + li) * 128 + ((ks * 64 + g * 16) ^ swz)));
#pragma unroll
                for (int mi = 0; mi < 2; ++mi)
#pragma unroll
                    for (int ni = 0; ni < 4; ++ni)
                        sacc[mi][ni] = __builtin_amdgcn_mfma_f32_16x16x32_bf16(
                            bk[ni], aq[mi][ks], sacc[mi][ni], 0, 0, 0);
            }
            __builtin_amdgcn_s_setprio(0);
        }

        // ---- p = exp2(s^T + bias'); packed bf16 pairs -> Pl; scalar l ----
        // lane: q = w*32 + mi*16 + li ; kk = kt*64 + ni*16 + g*4 + reg
#pragma unroll
        for (int mi = 0; mi < 2; ++mi) {
            const int idxC = kt * 64 + g * 4 - (w * 32 + mi * 16 + li) + 127;
            float p[4][4];   // [ni][reg]
#pragma unroll
            for (int reg = 0; reg < 4; ++reg) {
                const float* lbp = ldsb + idxC + reg;
                p[0][reg] = exp2_fast(sacc[mi][0][reg] + lbp[0]);
                p[1][reg] = exp2_fast(sacc[mi][1][reg] + lbp[16]);
                p[2][reg] = exp2_fast(sacc[mi][2][reg] + lbp[32]);
                p[3][reg] = exp2_fast(sacc[mi][3][reg] + lbp[48]);
                lp[mi] += (p[0][reg] + p[1][reg]) + (p[2][reg] + p[3][reg]);
            }
#pragma unroll
            for (int ni = 0; ni < 4; ++ni) {
                unsigned int lo = cvt_pk_bf16(p[ni][0], p[ni][1]);
                unsigned int hi = cvt_pk_bf16(p[ni][2], p[ni][3]);
                *(uint2*)&Pl[w][(mi * 16 + li) * PL_STR + ni * 16 + g * 4] =
                    make_uint2(lo, hi);
            }
        }

        // ---- O += P V (V frags from LDS; skip OOB tiles: V == 0) ----
        if (inb) {
            __builtin_amdgcn_s_setprio(1);
#pragma unroll
            for (int ks = 0; ks < 2; ++ks) {
                bf16x8 ap[2], bv[4];
#pragma unroll
                for (int mi = 0; mi < 2; ++mi)
                    ap[mi] = *(bf16x8*)&Pl[w][(mi * 16 + li) * PL_STR + ks * 32 + g * 8];
#pragma unroll
                for (int dn = 0; dn < 4; ++dn)
                    bv[dn] = *(const bf16x8*)(vbufC +
                        ((dn * 16 + li) * 128 + ((ks * 64 + g * 16) ^ swz)));
#pragma unroll
                for (int mi = 0; mi < 2; ++mi)
#pragma unroll
                    for (int dn = 0; dn < 4; ++dn)
                        oacc[mi][dn] = __builtin_amdgcn_mfma_f32_16x16x32_bf16(
                            ap[mi], bv[dn], oacc[mi][dn], 0, 0, 0);
            }
            __builtin_amdgcn_s_setprio(0);
        }

        __syncthreads();   // next-tile stage drained; buf[cur] free for reuse
    }

    // ---- deferred l-reduce (across g) + redistribute + write out ----
#pragma unroll
    for (int mi = 0; mi < 2; ++mi) {
        float l = lp[mi];
        l += __shfl_xor(l, 16);
        l += __shfl_xor(l, 32);   // now lane holds full l for q = mi*16+li
#pragma unroll
        for (int reg = 0; reg < 4; ++reg) {
            float inv = 1.f / __shfl(l, g * 4 + reg);  // l of row g*4+reg
            int t = n * BLK + w * 32 + mi * 16 + g * 4 + reg;
            unsigned short* orow = ao + ((size_t)b * T_LEN + t) * CDIM + h * HDIM;
#pragma unroll
            for (int dn = 0; dn < 4; ++dn)
                orow[dn * 16 + li] = f2b(oacc[mi][dn][reg] * inv);
        }
    }
#undef STAGEKV
}

extern "C" void kernel_launch(void* const* d_in, const int* in_sizes, int n_in,
                              void* d_out, int out_size, void* d_ws, size_t ws_size,
                              hipStream_t stream) {
    const float* hidden = (const float*)d_in[0];
    const float* Wq = (const float*)d_in[1];
    const float* Wk = (const float*)d_in[2];
    const float* Wv = (const float*)d_in[3];
    const float* Wo = (const float*)d_in[4];
    const float* table = (const float*)d_in[5];
    float* out = (float*)d_out;

    const size_t qkvElems = (size_t)BATCH * NHEAD * T_LEN * HDIM;   // 16.78M
    const size_t wElems = (size_t)CDIM * CDIM;                      // 1.05M
    const size_t needed = (4 * qkvElems + 4 * wElems) * 2;          // ~136 MiB
    if (ws_size < needed) return;

    unsigned short* qb = (unsigned short*)d_ws;
    unsigned short* kb = qb + qkvElems;
    unsigned short* vT = kb + qkvElems;     // [b][h][d][t]
    unsigned short* xb = vT + qkvElems;     // reused as ao after proj
    unsigned short* wt = xb + qkvElems;     // [WqT|WkT|WvT|WoT], each [1024][1024]

    conv_xw<<<12288, 256, 0, stream>>>(hidden, Wq, Wk, Wv, Wo, xb, wt);
    gemm_8ph<3><<<dim3(64, 12), 512, 0, stream>>>(xb, wt, qb, kb, vT, nullptr);
    attn_mfma<<<NBLK * NHEAD * BATCH, 256, 0, stream>>>(qb, kb, vT, table, xb);
    gemm_8ph<1><<<dim3(64, 4), 512, 0, stream>>>(xb, wt + 3 * wElems,
                                                 nullptr, nullptr, nullptr, out);
}